// Round 17
// baseline (129.914 us; speedup 1.0000x reference)
//
#include <hip/hip_runtime.h>
#include <hip/hip_bf16.h>

#define N_NODES 50000
#define N_EDGES 800000
#define D_IN 96
#define D_OUT 128
#define CAP 64              // deg ~ Poisson(16); P(deg>=64) ~ e^-41 -> no drops
#define CAPP 72             // bkt row pitch (u16): 144 B = 9*16 B (b128-aligned)

#define NPB 50                                      // nodes per bin/agg block
#define N_BINS ((N_NODES + NPB - 1) / NPB)          // 1000 exactly
#define NB_PAD 1024                                 // LDS arrays padded
#define PART_EPB 3125
#define PART_BLOCKS (N_EDGES / PART_EPB)            // 256 exactly
#define PART_SLOTS 13                               // ceil(3125/256)

#define CONV_THREADS (N_NODES * 12)                 // 600000
#define CONV_BLOCKS ((CONV_THREADS + 255) / 256)    // 2344
#define WCONV_BLOCKS 12                             // 128*24 = 3072 tasks

#define AG_BLOCKS N_BINS                            // 1000
#define AH_PITCH 104        // u16/row (96+8 pad); 208 B = 13*16 B

typedef unsigned short u16;
typedef __attribute__((ext_vector_type(8))) short short8;   // 8 x bf16
typedef __attribute__((ext_vector_type(4))) float f32x4;

__device__ __forceinline__ u16 f2bf(float f) {
    unsigned u = __float_as_uint(f);
    unsigned r = (u + 0x7FFFu + ((u >> 16) & 1u)) >> 16;   // RNE
    return (u16)r;
}
__device__ __forceinline__ float bf2f(u16 h) {
    return __uint_as_float(((unsigned)h) << 16);
}

// ---------------------------------------------------------------------------
// K1: heterogeneous grid.
//   [0, PART_BLOCKS): COMPACT counting-sort partition. R16 accounting: the
//     old fixed-cell scatter wrote ~400 KB/block of partial lines (102 MB
//     total) — same write-amplification bug as R0's fill, hidden in K1.
//     Now: LDS histogram -> LDS prefix-scan -> scatter into LDS (12.5 KB)
//     -> ONE coalesced 12.5 KB compact write per block + block-major
//     cnts/offs. Zero scattered global writes, zero device atomics.
//   [.., +CONV_BLOCKS): xh = bf16(x), monolithic 192 B rows (line-aligned).
//   [.., +WCONV_BLOCKS): Wfrag = bf16 B-fragment-layout [Wl|Wr].
// ---------------------------------------------------------------------------
__global__ __launch_bounds__(256) void sage_part_conv(
    const int* __restrict__ src,
    const int* __restrict__ dst,
    const float* __restrict__ x,
    const float* __restrict__ Wl,
    const float* __restrict__ Wr,
    u16* __restrict__ cnts,
    u16* __restrict__ offs,
    unsigned* __restrict__ compact,
    u16* __restrict__ xh,
    u16* __restrict__ Wfrag)
{
    __shared__ unsigned hist[NB_PAD];
    __shared__ unsigned cur[NB_PAD];
    __shared__ unsigned base_l[NB_PAD];
    __shared__ unsigned totals[256];
    __shared__ unsigned edges_l[PART_EPB];          // 12500 B (total ~25.4 KB)

    const int b = blockIdx.x;
    const int tid = (int)threadIdx.x;

    if (b < PART_BLOCKS) {
        for (int i = tid; i < NB_PAD; i += 256) { hist[i] = 0u; cur[i] = 0u; }
        __syncthreads();

        const int ebase = b * PART_EPB;
        const int e0 = ebase + tid;
        int d[PART_SLOTS], s[PART_SLOTS];
#pragma unroll
        for (int i = 0; i < PART_SLOTS; i++) {      // coalesced batch loads
            int valid = (tid + i * 256) < PART_EPB;
            int e = valid ? (e0 + i * 256) : ebase;
            d[i] = dst[e];
            s[i] = src[e];
        }
#pragma unroll
        for (int i = 0; i < PART_SLOTS; i++) {
            if ((tid + i * 256) < PART_EPB)
                atomicAdd(&hist[d[i] / NPB], 1u);   // LDS atomic (magic-mul)
        }
        __syncthreads();

        // ---- exclusive prefix scan over 1024 padded bins (4 per thread) --
        unsigned s0 = hist[4 * tid + 0];
        unsigned s1 = hist[4 * tid + 1];
        unsigned s2 = hist[4 * tid + 2];
        unsigned s3 = hist[4 * tid + 3];
        totals[tid] = s0 + s1 + s2 + s3;
        __syncthreads();
        for (int st = 1; st < 256; st <<= 1) {      // Hillis-Steele inclusive
            unsigned v = (tid >= st) ? totals[tid - st] : 0u;
            __syncthreads();
            totals[tid] += v;
            __syncthreads();
        }
        unsigned tb = tid ? totals[tid - 1] : 0u;   // exclusive over 4-groups
        base_l[4 * tid + 0] = tb;
        base_l[4 * tid + 1] = tb + s0;
        base_l[4 * tid + 2] = tb + s0 + s1;
        base_l[4 * tid + 3] = tb + s0 + s1 + s2;
        __syncthreads();

        // counts + offsets, block-major -> fully coalesced u16 stores
        for (int i = tid; i < N_BINS; i += 256) {
            cnts[(size_t)b * N_BINS + i] = (u16)hist[i];
            offs[(size_t)b * N_BINS + i] = (u16)base_l[i];
        }

        // scatter edges into LDS at sorted positions
#pragma unroll
        for (int i = 0; i < PART_SLOTS; i++) {
            if ((tid + i * 256) < PART_EPB) {
                int bn = d[i] / NPB;
                unsigned dl = (unsigned)(d[i] - bn * NPB);   // < 50
                unsigned pos = base_l[bn] + atomicAdd(&cur[bn], 1u);
                if (pos < PART_EPB)                 // provably true; safety
                    edges_l[pos] = (dl << 16) | (unsigned)s[i];
            }
        }
        __syncthreads();

        // coalesced compact write: 3125 u32 = 12.5 KB, full lines
        for (int i = tid; i < PART_EPB; i += 256)
            compact[(size_t)b * PART_EPB + i] = edges_l[i];
    } else if (b < PART_BLOCKS + CONV_BLOCKS) {
        unsigned t = (unsigned)(b - PART_BLOCKS) * 256u + threadIdx.x;
        if (t >= (unsigned)CONV_THREADS) return;
        unsigned n = t / 12u;
        unsigned c8 = t - n * 12u;
        const float* p = x + (size_t)n * D_IN + c8 * 8u;
        short8 v;
#pragma unroll
        for (int i = 0; i < 8; i++) v[i] = (short)f2bf(p[i]);
        *(short8*)(xh + (size_t)n * D_IN + c8 * 8u) = v;
    } else {
        // W -> bf16 fragments: 128 j x 24 chunks (12 Wl + 12 Wr)
        int idx = (b - PART_BLOCKS - CONV_BLOCKS) * 256 + tid;   // < 3072
        int j = idx / 24;
        int c8 = idx - j * 24;
        int kc = c8 >> 2;
        int quad = c8 & 3;
        const float* wsrc = (c8 < 12) ? (Wl + (size_t)j * D_IN + c8 * 8)
                                      : (Wr + (size_t)j * D_IN + (c8 - 12) * 8);
        int jt = j >> 4;
        int col = j & 15;
        short8 v;
#pragma unroll
        for (int i = 0; i < 8; i++) v[i] = (short)f2bf(wsrc[i]);
        *(short8*)(Wfrag + (((jt * 6 + kc) * 64) + col + 16 * quad) * 8) = v;
    }
}

// ---------------------------------------------------------------------------
// K2 (512-thread; phase A/B byte-identical to R16's measured 46.08):
// block j owns nodes [j*50, +50). Prologue now ingests from the compact
// per-part-block slices (cnt/off lookups, avg ~3 u32 reads per thread,
// L2/L3-resident 3.2 MB).
// ---------------------------------------------------------------------------
__global__ __launch_bounds__(512) void sage_agg_gemm(
    const u16* __restrict__ xh,
    const u16* __restrict__ cnts,
    const u16* __restrict__ offs,
    const unsigned* __restrict__ compact,
    const u16* __restrict__ Wfrag,
    const float* __restrict__ bl,
    float* __restrict__ out)
{
    __shared__ __align__(16) u16 bkt[NPB * CAPP];   // 7200 B (padded rows)
    __shared__ unsigned cnt_l[NPB];                 // 200 B
    __shared__ __align__(16) u16 Ah[NPB * AH_PITCH];// 10400 B (total ~17.8 KB)

    const int j = blockIdx.x;                       // bin == block
    const int tid = (int)threadIdx.x;
    const int n0 = j * NPB;

    if (tid < NPB) cnt_l[tid] = 0u;
    __syncthreads();

    // ---- prologue: threads 0-255 ingest compact slices (t = pblock t) ----
    if (tid < PART_BLOCKS) {
        unsigned cnt = cnts[(size_t)tid * N_BINS + j];
        unsigned off = offs[(size_t)tid * N_BINS + j];
        const unsigned* cp = compact + (size_t)tid * PART_EPB + off;
        for (unsigned k = 0; k < cnt; k++) {
            unsigned w = cp[k];
            unsigned r = w >> 16;                   // local node, < 50
            unsigned p = atomicAdd(&cnt_l[r], 1u);
            if (p < CAP) bkt[r * CAPP + p] = (u16)(w & 0xFFFFu);
        }
    }
    __syncthreads();

    // ---- phase A: pair=(m,c8) on adjacent lanes; 600 pairs over 3 reps ---
#pragma unroll
    for (int rep = 0; rep < 3; rep++) {
        int pair = rep * 256 + (tid >> 1);   // 0..767 (>=600 masked)
        int m = pair / 12;                   // node 0..63 (>=50 masked)
        int c8 = pair - m * 12;              // chunk 0..11
        int half = tid & 1;

        float acc[8];
#pragma unroll
        for (int i = 0; i < 8; i++) acc[i] = 0.0f;
        int deg = 0;

        if (m < NPB) {                       // masked tasks skip entirely
            deg = (int)cnt_l[m];
            int dc = deg < CAP ? deg : CAP;
            // 8-ALIGNED split (ds_read_b128 needs 16B-aligned LDS addr):
            int mid = ((dc >> 1) + 4) & ~7;  // provably <= dc
            int e_lo = half ? mid : 0;
            int e_hi = half ? dc : mid;
            const u16* brow = bkt + m * CAPP;       // LDS (144B-pitch rows)
            int e = e_lo;                           // multiple of 8
            for (; e + 8 <= e_hi; e += 8) {
                short8 id = *(const short8*)(brow + e);   // aligned LDS b128
                short8 v[8];
#pragma unroll
                for (int q = 0; q < 8; q++) {
                    unsigned s = (u16)id[q];
                    v[q] = *(const short8*)(xh + s * (unsigned)D_IN + c8 * 8u);
                }
#pragma unroll
                for (int q = 0; q < 8; q++)
#pragma unroll
                    for (int i = 0; i < 8; i++) acc[i] += bf2f((u16)v[q][i]);
            }
            if (e + 4 <= e_hi) {                    // scalar u16 index reads
                unsigned s0 = brow[e + 0];
                unsigned s1 = brow[e + 1];
                unsigned s2 = brow[e + 2];
                unsigned s3 = brow[e + 3];
                short8 v0 = *(const short8*)(xh + s0 * (unsigned)D_IN + c8 * 8u);
                short8 v1 = *(const short8*)(xh + s1 * (unsigned)D_IN + c8 * 8u);
                short8 v2 = *(const short8*)(xh + s2 * (unsigned)D_IN + c8 * 8u);
                short8 v3 = *(const short8*)(xh + s3 * (unsigned)D_IN + c8 * 8u);
#pragma unroll
                for (int i = 0; i < 8; i++)
                    acc[i] += bf2f((u16)v0[i]) + bf2f((u16)v1[i])
                            + bf2f((u16)v2[i]) + bf2f((u16)v3[i]);
                e += 4;
            }
            for (; e < e_hi; e++) {
                unsigned s = brow[e];
                short8 v = *(const short8*)(xh + s * (unsigned)D_IN + c8 * 8u);
#pragma unroll
                for (int i = 0; i < 8; i++) acc[i] += bf2f((u16)v[i]);
            }
        }

        // merge halves across adjacent lanes (convergent: all lanes execute)
#pragma unroll
        for (int i = 0; i < 8; i++)
            acc[i] += __shfl_xor(acc[i], 1);

        if (half == 0 && m < NPB) {          // even lane finalizes + writes
            float invd = 1.0f / fmaxf((float)deg, 1.0f);
            short8 o;
#pragma unroll
            for (int i = 0; i < 8; i++)
                o[i] = (short)f2bf(acc[i] * invd);
            *(short8*)(Ah + m * AH_PITCH + c8 * 8) = o;
        }
    }
    __syncthreads();

    // ---- phase B: 8 waves; wave w = (tile w&3, jt-quad w>>2) ----
    const int wave = tid >> 6;
    const int lane = tid & 63;
    const int m16 = lane & 15;
    const int quad = lane >> 4;
    const int tile = wave & 3;
    const int jt0 = (wave >> 2) * 4;

    int mrow = tile * 16 + m16;              // 0..63
    int mclamp = mrow < NPB ? mrow : NPB - 1;       // clamp LDS/x sources
    int nn = n0 + mclamp;                    // < N_NODES by construction

    const u16* arow = Ah + mclamp * AH_PITCH + quad * 8;
    const u16* xrow = xh + (size_t)nn * D_IN + quad * 8;
    short8 a[6];
#pragma unroll
    for (int kc = 0; kc < 3; kc++) a[kc]     = *(const short8*)(arow + kc * 32);
#pragma unroll
    for (int kc = 0; kc < 3; kc++) a[3 + kc] = *(const short8*)(xrow + kc * 32);

#pragma unroll
    for (int jt = 0; jt < 4; jt++) {
        const int jtt = jt0 + jt;
        f32x4 acc = {0.0f, 0.0f, 0.0f, 0.0f};
#pragma unroll
        for (int kc = 0; kc < 6; kc++) {
            short8 bfrag = *(const short8*)(Wfrag + ((jtt * 6 + kc) * 64 + lane) * 8);
            acc = __builtin_amdgcn_mfma_f32_16x16x32_bf16(a[kc], bfrag, acc, 0, 0, 0);
        }
        const int jj = jtt * 16 + m16;       // col = lane&15
        const float bj = bl[jj];
#pragma unroll
        for (int r = 0; r < 4; r++) {
            int row = tile * 16 + quad * 4 + r;     // 0..63
            if (row < NPB)                   // rows >= 50 belong to next bin
                out[(size_t)(n0 + row) * D_OUT + jj] = fmaxf(acc[r] + bj, 0.0f);
        }
    }
}

extern "C" void kernel_launch(void* const* d_in, const int* in_sizes, int n_in,
                              void* d_out, int out_size, void* d_ws, size_t ws_size,
                              hipStream_t stream) {
    const float* x   = (const float*)d_in[0];
    const int* eidx  = (const int*)d_in[1];
    const float* Wl  = (const float*)d_in[2];
    const float* bl  = (const float*)d_in[3];
    const float* Wr  = (const float*)d_in[4];
    float* out = (float*)d_out;

    const int* src = eidx;                // edge_index[0]
    const int* dst = eidx + N_EDGES;      // edge_index[1]

    // ws layout (byte offsets) — no zero-init needed anywhere:
    //   compact   0          12,800,000 B (256 * 3125 u32, fully written)
    //   cnts      12,800,000    512,000 B (256*1000 u16, block-major)
    //   offs      13,312,000    512,000 B (256*1000 u16, block-major)
    //   xh        13,824,000  9,600,000 B (bf16, monolithic 192 B rows)
    //   Wfrag     23,424,000     49,152 B
    char* ws = (char*)d_ws;
    unsigned* compact = (unsigned*)ws;
    u16*      cnts    = (u16*)(ws + 12800000);
    u16*      offs    = (u16*)(ws + 13312000);
    u16*      xh      = (u16*)(ws + 13824000);
    u16*      Wfrag   = (u16*)(ws + 23424000);

    {
        dim3 grid(PART_BLOCKS + CONV_BLOCKS + WCONV_BLOCKS);   // 2612
        sage_part_conv<<<grid, 256, 0, stream>>>(src, dst, x, Wl, Wr,
                                                 cnts, offs, compact, xh, Wfrag);
    }
    {
        dim3 grid(AG_BLOCKS);                                  // 1000
        sage_agg_gemm<<<grid, 512, 0, stream>>>(xh, cnts, offs, compact,
                                                Wfrag, bl, out);
    }
}

// Round 19
// 122.982 us; speedup vs baseline: 1.0564x; 1.0564x over previous
//
#include <hip/hip_runtime.h>
#include <hip/hip_bf16.h>

#define N_NODES 50000
#define N_EDGES 800000
#define D_IN 96
#define D_OUT 128
#define CAP 64              // deg ~ Poisson(16); P(deg>=64) ~ e^-41 -> no drops

// Deterministic partition: bins of 64 nodes (== agg block), each
// (part-block, bin) cell owns a FIXED 24-slot sub-chunk of binbuf plus a
// plain-store count. Zero device atomics, zero memset. R2/R4 lessons:
// 800K device atomics = 45us wall; bin granularity must match consumer.
// SESSION-BEST CONFIG (R9: 124.6us). R12-R18 post-mortems: agg is at the
// cross-XCD gather roofline (FETCH == 8 XCDs x 9.6MB xh, ~2.3 TB/s random
// line rate; invariant across 7 structural variants), K1 compact rewrite
// null, cooperative fusion non-viable in harness. Reverted to this.
#define NPB 64                                      // nodes per bin/agg block
#define N_BINS ((N_NODES + NPB - 1) / NPB)          // 782
#define CAP_SUB 24          // edges per (pblock,bin); lambda=4 -> P(ovf) ~3e-7
#define PART_EPB 3125
#define PART_BLOCKS (N_EDGES / PART_EPB)            // 256 exactly
#define PART_SLOTS 13                               // ceil(3125/256)

#define CONV_THREADS (N_NODES * 12)                 // 600000
#define CONV_BLOCKS ((CONV_THREADS + 255) / 256)    // 2344
#define WCONV_BLOCKS 12                             // 128*24 = 3072 = 12*256 tasks

#define AG_BLOCKS N_BINS                            // 782
#define AH_PITCH 104        // u16/row (96+8 pad); 208 B = 13*16 B (b128-aligned)

typedef unsigned short u16;
typedef __attribute__((ext_vector_type(8))) short short8;   // 8 x bf16 (4 VGPRs)
typedef __attribute__((ext_vector_type(4))) float f32x4;

__device__ __forceinline__ u16 f2bf(float f) {
    unsigned u = __float_as_uint(f);
    unsigned r = (u + 0x7FFFu + ((u >> 16) & 1u)) >> 16;   // RNE
    return (u16)r;
}
__device__ __forceinline__ float bf2f(u16 h) {
    return __uint_as_float(((unsigned)h) << 16);
}

// ---------------------------------------------------------------------------
// K1: heterogeneous grid.
//   [0, PART_BLOCKS): deterministic partition. 13-slot ILP batch loads
//     (R2-proven) -> LDS histogram over 782 bins (bin = d>>6, no division) ->
//     plain-store counts to cnts[bin][pblock] -> scatter packed (dl<<16|src)
//     into fixed sub-chunk binbuf[(bin*256+pb)*24 + loc]. NO device atomics,
//     NO memset dependency.
//   [.., +CONV_BLOCKS): xh = bf16(x) row-major.
//   [.., +WCONV_BLOCKS): Wfrag = bf16 B-fragment-layout [Wl|Wr] in global ws.
// ---------------------------------------------------------------------------
__global__ __launch_bounds__(256) void sage_part_conv(
    const int* __restrict__ src,
    const int* __restrict__ dst,
    const float* __restrict__ x,
    const float* __restrict__ Wl,
    const float* __restrict__ Wr,
    u16* __restrict__ cnts,
    unsigned* __restrict__ binbuf,
    u16* __restrict__ xh,
    u16* __restrict__ Wfrag)
{
    __shared__ unsigned hist[N_BINS];
    __shared__ unsigned cur[N_BINS];

    const int b = blockIdx.x;
    const int tid = (int)threadIdx.x;

    if (b < PART_BLOCKS) {
        for (int i = tid; i < N_BINS; i += 256) { hist[i] = 0u; cur[i] = 0u; }
        __syncthreads();

        const int ebase = b * PART_EPB;
        const int e0 = ebase + tid;
        int d[PART_SLOTS], s[PART_SLOTS];
#pragma unroll
        for (int i = 0; i < PART_SLOTS; i++) {      // coalesced batch loads
            int valid = (tid + i * 256) < PART_EPB;
            int e = valid ? (e0 + i * 256) : ebase;
            d[i] = dst[e];
            s[i] = src[e];
        }
#pragma unroll
        for (int i = 0; i < PART_SLOTS; i++) {
            if ((tid + i * 256) < PART_EPB)
                atomicAdd(&hist[d[i] >> 6], 1u);    // LDS atomic (cheap)
        }
        __syncthreads();
        for (int i = tid; i < N_BINS; i += 256)     // plain-store counts
            cnts[(size_t)i * PART_BLOCKS + b] = (u16)hist[i];
#pragma unroll
        for (int i = 0; i < PART_SLOTS; i++) {
            if ((tid + i * 256) < PART_EPB) {
                int bn = d[i] >> 6;
                unsigned dl = (unsigned)(d[i] & 63);
                unsigned loc = atomicAdd(&cur[bn], 1u);      // LDS atomic
                if (loc < CAP_SUB)                  // ~3e-7 overflow guard
                    binbuf[((unsigned)bn * PART_BLOCKS + (unsigned)b) * CAP_SUB
                           + loc] = (dl << 16) | (unsigned)s[i];
            }
        }
    } else if (b < PART_BLOCKS + CONV_BLOCKS) {
        unsigned t = (unsigned)(b - PART_BLOCKS) * 256u + threadIdx.x;
        if (t >= (unsigned)CONV_THREADS) return;
        unsigned n = t / 12u;
        unsigned c8 = t - n * 12u;
        const float* p = x + (size_t)n * D_IN + c8 * 8u;
        short8 v;
#pragma unroll
        for (int i = 0; i < 8; i++) v[i] = (short)f2bf(p[i]);
        *(short8*)(xh + (size_t)n * D_IN + c8 * 8u) = v;
    } else {
        // W -> bf16 fragments: 128 j x 24 chunks (12 Wl + 12 Wr)
        int idx = (b - PART_BLOCKS - CONV_BLOCKS) * 256 + tid;   // < 3072
        int j = idx / 24;
        int c8 = idx - j * 24;
        int kc = c8 >> 2;
        int quad = c8 & 3;
        const float* wsrc = (c8 < 12) ? (Wl + (size_t)j * D_IN + c8 * 8)
                                      : (Wr + (size_t)j * D_IN + (c8 - 12) * 8);
        int jt = j >> 4;
        int col = j & 15;
        short8 v;
#pragma unroll
        for (int i = 0; i < 8; i++) v[i] = (short)f2bf(wsrc[i]);
        *(short8*)(Wfrag + (((jt * 6 + kc) * 64) + col + 16 * quad) * 8) = v;
    }
}

// ---------------------------------------------------------------------------
// K2 (fused bin+agg+gemm): block j owns nodes [j*64, +64).
// Prologue: thread t ingests sub-chunk (j, pblock=t): 6 independent uint4
//   loads (96 B, all in flight), then fully-unrolled static-index appends
//   into an 8 KB LDS bucket via LDS atomics (rule #20: no runtime-indexed
//   register arrays). Kills the bucket/cursor global round-trip + a launch.
// Phase A: 768 tasks (node m, chunk c8), 3/thread; bucket rows read from
//   LDS (b128), 8 xh row-gathers in flight.
// Phase B: per-wave 16-node MFMA tile; A-frags Ah/xh, B-frags Wfrag
//   (L2-broadcast). C/D map col=lane&15, row=quad*4+r (m89/m91-verified).
// ---------------------------------------------------------------------------
__global__ __launch_bounds__(256) void sage_agg_gemm(
    const u16* __restrict__ xh,
    const u16* __restrict__ cnts,
    const unsigned* __restrict__ binbuf,
    const u16* __restrict__ Wfrag,
    const float* __restrict__ bl,
    float* __restrict__ out)
{
    __shared__ __align__(16) u16 bkt[NPB * CAP];    // 8192 B
    __shared__ unsigned cnt_l[NPB];
    __shared__ u16 Ah[NPB * AH_PITCH];              // 13312 B

    const int j = blockIdx.x;                       // bin == block
    const int tid = (int)threadIdx.x;
    const int n0 = j * NPB;

    if (tid < NPB) cnt_l[tid] = 0u;
    __syncthreads();

    // ---- prologue: ingest this bin's 256 sub-chunks (thread t = pblock t) --
    {
        unsigned cnt_t = cnts[(size_t)j * PART_BLOCKS + tid];
        const uint4* sc = (const uint4*)(binbuf
                          + ((size_t)j * PART_BLOCKS + tid) * CAP_SUB);
        uint4 q0 = sc[0], q1 = sc[1], q2 = sc[2], q3 = sc[3], q4 = sc[4], q5 = sc[5];
        unsigned buf[CAP_SUB];
        buf[0]=q0.x;  buf[1]=q0.y;  buf[2]=q0.z;  buf[3]=q0.w;
        buf[4]=q1.x;  buf[5]=q1.y;  buf[6]=q1.z;  buf[7]=q1.w;
        buf[8]=q2.x;  buf[9]=q2.y;  buf[10]=q2.z; buf[11]=q2.w;
        buf[12]=q3.x; buf[13]=q3.y; buf[14]=q3.z; buf[15]=q3.w;
        buf[16]=q4.x; buf[17]=q4.y; buf[18]=q4.z; buf[19]=q4.w;
        buf[20]=q5.x; buf[21]=q5.y; buf[22]=q5.z; buf[23]=q5.w;
        unsigned lim = cnt_t < CAP_SUB ? cnt_t : CAP_SUB;
#pragma unroll
        for (int e = 0; e < CAP_SUB; e++) {         // static indices only
            if ((unsigned)e < lim) {
                unsigned w = buf[e];
                unsigned r = w >> 16;               // local node, < 64
                unsigned p = atomicAdd(&cnt_l[r], 1u);
                if (p < CAP) bkt[r * CAP + p] = (u16)(w & 0xFFFFu);
            }
        }
    }
    __syncthreads();

    // ---- phase A: aggregate the block's 64 nodes into Ah ----
#pragma unroll
    for (int rep = 0; rep < 3; rep++) {
        int task = rep * 256 + tid;          // 0..767
        int m = task / 12;
        int c8 = task - m * 12;
        int n = n0 + m;

        float acc[8];
#pragma unroll
        for (int i = 0; i < 8; i++) acc[i] = 0.0f;
        float invd = 0.0f;

        if (n < N_NODES) {
            int deg = (int)cnt_l[m];
            int degc = deg < CAP ? deg : CAP;
            const u16* brow = bkt + m * CAP;        // LDS
            int e = 0;
            for (; e + 8 <= degc; e += 8) {
                short8 id = *(const short8*)(brow + e);   // one LDS b128
                short8 v[8];
#pragma unroll
                for (int q = 0; q < 8; q++) {
                    unsigned s = (u16)id[q];
                    v[q] = *(const short8*)(xh + s * (unsigned)D_IN + c8 * 8u);
                }
#pragma unroll
                for (int q = 0; q < 8; q++)
#pragma unroll
                    for (int i = 0; i < 8; i++) acc[i] += bf2f((u16)v[q][i]);
            }
            if (e + 4 <= degc) {
                unsigned s0 = brow[e + 0];
                unsigned s1 = brow[e + 1];
                unsigned s2 = brow[e + 2];
                unsigned s3 = brow[e + 3];
                short8 v0 = *(const short8*)(xh + s0 * (unsigned)D_IN + c8 * 8u);
                short8 v1 = *(const short8*)(xh + s1 * (unsigned)D_IN + c8 * 8u);
                short8 v2 = *(const short8*)(xh + s2 * (unsigned)D_IN + c8 * 8u);
                short8 v3 = *(const short8*)(xh + s3 * (unsigned)D_IN + c8 * 8u);
#pragma unroll
                for (int i = 0; i < 8; i++)
                    acc[i] += bf2f((u16)v0[i]) + bf2f((u16)v1[i])
                            + bf2f((u16)v2[i]) + bf2f((u16)v3[i]);
                e += 4;
            }
            for (; e < degc; e++) {
                unsigned s = brow[e];
                short8 v = *(const short8*)(xh + s * (unsigned)D_IN + c8 * 8u);
#pragma unroll
                for (int i = 0; i < 8; i++) acc[i] += bf2f((u16)v[i]);
            }
            invd = 1.0f / fmaxf((float)deg, 1.0f);
        }

        short8 o;
#pragma unroll
        for (int i = 0; i < 8; i++) o[i] = (short)f2bf(acc[i] * invd);
        *(short8*)(Ah + m * AH_PITCH + c8 * 8) = o;
    }
    __syncthreads();

    // ---- phase B: 16-node MFMA tile per wave ----
    const int wave = tid >> 6;
    const int lane = tid & 63;
    const int m16 = lane & 15;
    const int quad = lane >> 4;
    const int tilebase = n0 + wave * 16;
    if (tilebase >= N_NODES) return;         // all barriers already passed

    int nn = tilebase + m16;
    nn = nn < N_NODES ? nn : N_NODES - 1;    // clamp A-row source (store guarded)

    const u16* arow = Ah + (wave * 16 + m16) * AH_PITCH + quad * 8;
    const u16* xrow = xh + (size_t)nn * D_IN + quad * 8;
    short8 a[6];
#pragma unroll
    for (int kc = 0; kc < 3; kc++) a[kc]     = *(const short8*)(arow + kc * 32);
#pragma unroll
    for (int kc = 0; kc < 3; kc++) a[3 + kc] = *(const short8*)(xrow + kc * 32);

#pragma unroll
    for (int jt = 0; jt < 8; jt++) {
        f32x4 acc = {0.0f, 0.0f, 0.0f, 0.0f};
#pragma unroll
        for (int kc = 0; kc < 6; kc++) {
            short8 bfrag = *(const short8*)(Wfrag + ((jt * 6 + kc) * 64 + lane) * 8);
            acc = __builtin_amdgcn_mfma_f32_16x16x32_bf16(a[kc], bfrag, acc, 0, 0, 0);
        }
        const int jj = jt * 16 + m16;        // col = lane&15
        const float bj = bl[jj];
#pragma unroll
        for (int r = 0; r < 4; r++) {
            int row = quad * 4 + r;
            int n = tilebase + row;
            if (n < N_NODES)
                out[(size_t)n * D_OUT + jj] = fmaxf(acc[r] + bj, 0.0f);
        }
    }
}

extern "C" void kernel_launch(void* const* d_in, const int* in_sizes, int n_in,
                              void* d_out, int out_size, void* d_ws, size_t ws_size,
                              hipStream_t stream) {
    const float* x   = (const float*)d_in[0];
    const int* eidx  = (const int*)d_in[1];
    const float* Wl  = (const float*)d_in[2];
    const float* bl  = (const float*)d_in[3];
    const float* Wr  = (const float*)d_in[4];
    float* out = (float*)d_out;

    const int* src = eidx;                // edge_index[0]
    const int* dst = eidx + N_EDGES;      // edge_index[1]

    // ws layout (byte offsets) — no zero-init needed anywhere:
    //   binbuf    0          19,218,432 B (782*256*24 u32, fixed sub-chunks)
    //   cnts      19,218,432    400,384 B (782*256 u16, fully overwritten)
    //   xh        19,618,816  9,600,000 B (bf16 x)        [16-aligned]
    //   Wfrag     29,218,816     49,152 B                  [16-aligned]
    char* ws = (char*)d_ws;
    unsigned* binbuf = (unsigned*)ws;
    u16*      cnts   = (u16*)(ws + 19218432);
    u16*      xh     = (u16*)(ws + 19618816);
    u16*      Wfrag  = (u16*)(ws + 29218816);

    {
        dim3 grid(PART_BLOCKS + CONV_BLOCKS + WCONV_BLOCKS);   // 2612
        sage_part_conv<<<grid, 256, 0, stream>>>(src, dst, x, Wl, Wr,
                                                 cnts, binbuf, xh, Wfrag);
    }
    {
        dim3 grid(AG_BLOCKS);                                  // 782
        sage_agg_gemm<<<grid, 256, 0, stream>>>(xh, cnts, binbuf, Wfrag, bl, out);
    }
}